// Round 22
// baseline (110.590 us; speedup 1.0000x reference)
//
#include <hip/hip_runtime.h>
#include <cstdint>
#include <cstddef>

// Problem: B=32, S=2048, D=512, H=512
//   sb[b,h]   = state @ W1[:D]
//   h         = tanh(tanh(sb + input@W1[D:]))   <-- DOUBLE tanh (reference quirk)
//   logit[b,s]= sum_h h * w2[h]  - 1e30*(1-mask)
//   p = softmax over S;  pooled[b,d] = sum_s p*input
// Outputs: pooled (16384 f32) ++ logit (65536 f32)
//
// r22: r21's verified fused kernel with the A-pipeline deepened to distance-3:
// ALOAD at p0/p2/p4/p6 (alternating avA/avB), AWRITE 3 phases later at
// p3/p5/p7/p1-next. Explicit vmcnt(4) after AWRITE at p3 (drains B(2i+1),
// leaves p2-batch) and p7 (drains B(2i+2), leaves p6-batch) — fixes r21's
// implicit-drain gap (waiting an older A-batch does NOT drain newer B).
// Region windows: A-partX last read at its q2 -> all writes (p3/p5/p7/p1) legal.

#define NEG_BIG 1e30f

typedef __attribute__((ext_vector_type(8))) short short8_t;   // 8 x bf16
typedef __attribute__((ext_vector_type(4))) float f32x4;

__device__ inline unsigned short f2bf(float f){
  union { float f; unsigned int u; } v; v.f = f;
  unsigned int r = v.u + 0x7fffu + ((v.u >> 16) & 1u);   // RNE
  return (unsigned short)(r >> 16);
}
// tanh via 1 - 2/(1+e^{2x}): exp overflow -> inf -> rcp -> 0 -> +1; underflow -> -1.
__device__ inline float tanh_cheap(float x){
  return 1.0f - 2.0f*__builtin_amdgcn_rcpf(1.0f + __expf(2.0f*x));
}

typedef __attribute__((address_space(1))) const unsigned int g_u32;
typedef __attribute__((address_space(3))) unsigned int l_u32;
__device__ inline void gload16(const void* g, void* l){
  __builtin_amdgcn_global_load_lds((g_u32*)g, (l_u32*)l, 16, 0, 0);
}

// ---------------------------------------------------------------- K0: prep (tiny)
__global__ __launch_bounds__(256) void k0_prep(const float* __restrict__ state,
                                               const float* __restrict__ W1,
                                               float* __restrict__ sbp,
                                               unsigned short* __restrict__ w1xt){
  const int bid = blockIdx.x, t = threadIdx.x;
  if (bid < 64) {
    const int k0 = (bid >> 3) * 64, h0 = (bid & 7) * 64;
    __shared__ float tile[64][65];
    const int c = t & 63, r0 = t >> 6;
    #pragma unroll
    for (int i = 0; i < 16; ++i){
      int r = r0 + 4*i;
      tile[r][c] = W1[(size_t)(512 + k0 + r)*512 + h0 + c];
    }
    __syncthreads();
    #pragma unroll
    for (int i = 0; i < 16; ++i){
      int r = r0 + 4*i;
      w1xt[(size_t)(h0 + r)*512 + k0 + c] = f2bf(tile[c][r]);
    }
  } else {
    const int idx = bid - 64;               // 0..255
    const int b = idx >> 3, ds = idx & 7;
    __shared__ float stl[64];
    if (t < 64) stl[t] = state[b*512 + ds*64 + t];
    __syncthreads();
    float acc0 = 0.f, acc1 = 0.f;
    #pragma unroll 8
    for (int i = 0; i < 64; ++i){
      const float w = stl[i];
      acc0 += w * W1[(size_t)(ds*64 + i)*512 + t];
      acc1 += w * W1[(size_t)(ds*64 + i)*512 + t + 256];
    }
    sbp[(size_t)(ds*32 + b)*512 + t]       = acc0;
    sbp[(size_t)(ds*32 + b)*512 + t + 256] = acc1;
  }
}

// ---------------------------------------------------------------- K1: 256x256 8-phase GEMM, distance-3 reg-cvt A
__global__ __launch_bounds__(512, 1) void k1_gemm_8ph(const float* __restrict__ input,
                                                      const unsigned short* __restrict__ w1xt,
                                                      const float* __restrict__ sbp,
                                                      const float* __restrict__ w2,
                                                      float* __restrict__ plog){
  __shared__ unsigned short lds[65536];   // 128 KB: buf(2) x [A 32KB | B 32KB]

  const int orig = blockIdx.x;            // 512 blocks, bijective XCD swizzle (512%8==0)
  const int xcd = orig & 7, qq = orig >> 3;
  const int mtile = xcd*32 + (qq >> 1);
  const int nt = qq & 1;                  // nt 0/1 of same mtile adjacent -> A L2 reuse
  const int m0 = mtile*256, n0 = nt*256;
  const int b = m0 >> 11;

  const int t = threadIdx.x;
  const int lane = t & 63, wid = t >> 6;
  const int wr = wid >> 2, wcn = wid & 3;
  const int lr = lane & 15, kg = lane >> 4;
  const int l7 = lr & 7;

  // B stage source (inverse-swizzled per-lane global addr; LDS dest linear)
  const int sl8 = ((lane & 7) ^ ((lane >> 3) & 7)) * 8;
  const unsigned short* gB = w1xt + (size_t)(n0 + wid*16 + (lane>>3))*512 + sl8;

  // A reg-stage mapping: thread covers row ar = PART*128 + (t>>2), f32 cols (t&3)*16..+15
  const int arq = t >> 2;                  // row within 128-row part
  const int acq = (t & 3) * 16;            // f32 col offset within K=64
  const int ar7 = arq & 7;                 // row&7 (PART*128 preserves &7)
  const int aq2 = (t & 3) * 2;             // logical 16B-chunk pair base

  // fragment read bases — byte-identical to verified r13/r20/r21
  const unsigned aBase = (unsigned)((wr*128 + lr)*64);
  const unsigned bBase = 16384u + (unsigned)((wcn*64 + lr)*64);
  const unsigned swz0 = (unsigned)(((0*4 + kg) ^ l7) * 8);   // ks=0
  const unsigned swz1 = (unsigned)(((1*4 + kg) ^ l7) * 8);   // ks=1

  f32x4 acc[8][4];
  #pragma unroll
  for (int mi = 0; mi < 8; ++mi)
    #pragma unroll
    for (int ni = 0; ni < 4; ++ni) acc[mi][ni] = (f32x4){0.f,0.f,0.f,0.f};

  short8_t af[4][2], bf[2][2];
  float4 avA0, avA1, avA2, avA3;           // batch A (load p0/p4, write p3/p7)
  float4 avB0, avB1, avB2, avB3;           // batch B (load p2/p6/prologue, write p5/p1)

#define ALOAD_A(KT, PART) do{ \
    const float* gs_ = input + (size_t)(m0 + (PART)*128 + arq)*512 + (KT)*64 + acq; \
    avA0 = *(const float4*)(gs_); \
    avA1 = *(const float4*)(gs_ + 4); \
    avA2 = *(const float4*)(gs_ + 8); \
    avA3 = *(const float4*)(gs_ + 12); }while(0)

#define ALOAD_B(KT, PART) do{ \
    const float* gs_ = input + (size_t)(m0 + (PART)*128 + arq)*512 + (KT)*64 + acq; \
    avB0 = *(const float4*)(gs_); \
    avB1 = *(const float4*)(gs_ + 4); \
    avB2 = *(const float4*)(gs_ + 8); \
    avB3 = *(const float4*)(gs_ + 12); }while(0)

#define AWRITE_X(V0,V1,V2,V3, KT, PART) do{ \
    unsigned u0_,u1_,u2_,u3_,u4_,u5_,u6_,u7_; \
    asm("v_cvt_pk_bf16_f32 %0, %1, %2" : "=v"(u0_) : "v"(V0.x), "v"(V0.y)); \
    asm("v_cvt_pk_bf16_f32 %0, %1, %2" : "=v"(u1_) : "v"(V0.z), "v"(V0.w)); \
    asm("v_cvt_pk_bf16_f32 %0, %1, %2" : "=v"(u2_) : "v"(V1.x), "v"(V1.y)); \
    asm("v_cvt_pk_bf16_f32 %0, %1, %2" : "=v"(u3_) : "v"(V1.z), "v"(V1.w)); \
    asm("v_cvt_pk_bf16_f32 %0, %1, %2" : "=v"(u4_) : "v"(V2.x), "v"(V2.y)); \
    asm("v_cvt_pk_bf16_f32 %0, %1, %2" : "=v"(u5_) : "v"(V2.z), "v"(V2.w)); \
    asm("v_cvt_pk_bf16_f32 %0, %1, %2" : "=v"(u6_) : "v"(V3.x), "v"(V3.y)); \
    asm("v_cvt_pk_bf16_f32 %0, %1, %2" : "=v"(u7_) : "v"(V3.z), "v"(V3.w)); \
    const unsigned ab_ = (unsigned)((((KT)&1)*32768) + ((PART)*128 + arq)*64); \
    uint4 w0_; w0_.x=u0_; w0_.y=u1_; w0_.z=u2_; w0_.w=u3_; \
    uint4 w1_; w1_.x=u4_; w1_.y=u5_; w1_.z=u6_; w1_.w=u7_; \
    *reinterpret_cast<uint4*>(&lds[ab_ + (unsigned)(((aq2    ) ^ ar7)*8)]) = w0_; \
    *reinterpret_cast<uint4*>(&lds[ab_ + (unsigned)(((aq2 + 1) ^ ar7)*8)]) = w1_; \
  }while(0)

#define AWRITE_A(KT, PART) AWRITE_X(avA0,avA1,avA2,avA3, KT, PART)
#define AWRITE_B(KT, PART) AWRITE_X(avB0,avB1,avB2,avB3, KT, PART)

#define STAGE_B(KT, PART) do{ \
    const unsigned short* gs_ = gB + (size_t)((PART)&1)*128*512 + (KT)*64; \
    unsigned short* ds_ = &lds[(unsigned)(((KT)&1)*32768 + 16384 + ((PART)&1)*8192 + wid*1024)]; \
    gload16(gs_,         ds_); \
    gload16(gs_ + 8*512, ds_ + 512); }while(0)

#define READ_A(mh, bo) do{ _Pragma("unroll") for (int mi = 0; mi < 4; ++mi){ \
    af[mi][0] = *(const short8_t*)&lds[(bo) + aBase + (unsigned)((mh)*4+mi)*1024 + swz0]; \
    af[mi][1] = *(const short8_t*)&lds[(bo) + aBase + (unsigned)((mh)*4+mi)*1024 + swz1]; } }while(0)

#define READ_B(nh, bo) do{ _Pragma("unroll") for (int ni = 0; ni < 2; ++ni){ \
    bf[ni][0] = *(const short8_t*)&lds[(bo) + bBase + (unsigned)((nh)*2+ni)*1024 + swz0]; \
    bf[ni][1] = *(const short8_t*)&lds[(bo) + bBase + (unsigned)((nh)*2+ni)*1024 + swz1]; } }while(0)

#define MFMA16(mh, nh) do{ \
    __builtin_amdgcn_s_setprio(1); \
    _Pragma("unroll") for (int mi = 0; mi < 4; ++mi) \
      _Pragma("unroll") for (int ni = 0; ni < 2; ++ni){ \
        acc[(mh)*4+mi][(nh)*2+ni] = __builtin_amdgcn_mfma_f32_16x16x32_bf16(af[mi][0], bf[ni][0], acc[(mh)*4+mi][(nh)*2+ni], 0,0,0); \
        acc[(mh)*4+mi][(nh)*2+ni] = __builtin_amdgcn_mfma_f32_16x16x32_bf16(af[mi][1], bf[ni][1], acc[(mh)*4+mi][(nh)*2+ni], 0,0,0); } \
    __builtin_amdgcn_s_setprio(0); }while(0)

  // prologue: B(0) async; A(0)p0/p1, A(1)p0 staged; A(1)p1 left in flight (avB)
  STAGE_B(0,2); STAGE_B(0,3);
  ALOAD_A(0,0); AWRITE_A(0,0);     // implicit drain (incl. B(0)) — prologue only
  ALOAD_A(0,1); AWRITE_A(0,1);
  ALOAD_A(1,0); AWRITE_A(1,0);
  ALOAD_B(1,1);                    // consumed at i=0 p1
  asm volatile("s_waitcnt lgkmcnt(0)" ::: "memory");
  __builtin_amdgcn_s_barrier();

  #pragma unroll
  for (int i = 0; i < 4; ++i){
    #pragma unroll
    for (int p = 0; p < 8; ++p){
      const int kt = 2*i + (p>>2);
      const unsigned bo = (unsigned)((kt & 1) * 32768);
      const int q = p & 3;
      // --- fragment ds-reads
      if (q == 0){ READ_A(0, bo); READ_B(0, bo); }
      else if (q == 1){ READ_B(1, bo); }
      else if (q == 2){ READ_A(1, bo); READ_B(0, bo); }
      else { READ_B(1, bo); }
      // --- stage ops (distance-3 ledger; header comment)
      if (p == 0){
        if (i < 3) ALOAD_A(2*i+2, 0);                       // avA; issued BEFORE B
        STAGE_B(2*i+1, 2); STAGE_B(2*i+1, 3);
      } else if (p == 1){
        AWRITE_B(2*i+1, 1);                                 // batch from prev p6 / prologue
      } else if (p == 2){
        if (i < 3) ALOAD_B(2*i+2, 1);
      } else if (p == 3){
        if (i < 3){ AWRITE_A(2*i+2, 0);                     // implicit: waits p0-batch
                    asm volatile("s_waitcnt vmcnt(4)" ::: "memory"); } // drain B(2i+1)
        else        asm volatile("s_waitcnt vmcnt(0)" ::: "memory");
      } else if (p == 4){
        if (i < 3){ ALOAD_A(2*i+3, 0);                      // avA; before B issue
                    STAGE_B(2*i+2, 2); STAGE_B(2*i+2, 3); }
      } else if (p == 5){
        if (i < 3) AWRITE_B(2*i+2, 1);                      // batch from p2
      } else if (p == 6){
        if (i < 3) ALOAD_B(2*i+3, 1);
      } else if (p == 7){
        if (i < 3){ AWRITE_A(2*i+3, 0);                     // implicit: waits p4-batch
                    asm volatile("s_waitcnt vmcnt(4)" ::: "memory"); } // drain B(2i+2)
      }
      __builtin_amdgcn_s_barrier();
      asm volatile("s_waitcnt lgkmcnt(0)" ::: "memory");
      __builtin_amdgcn_sched_barrier(0);
      MFMA16(q >> 1, q & 1);
      __builtin_amdgcn_s_barrier();
    }
  }
#undef ALOAD_A
#undef ALOAD_B
#undef AWRITE_X
#undef AWRITE_A
#undef AWRITE_B
#undef STAGE_B
#undef READ_A
#undef READ_B
#undef MFMA16

  // epilogue: tanh(tanh(acc + sb)) * w2, reduce over this block's 256 h-cols
  float w2v[4], sbv[4];
  #pragma unroll
  for (int ni = 0; ni < 4; ++ni){
    const int h = n0 + wcn*64 + ni*16 + lr;
    w2v[ni] = w2[h];
    float s = 0.f;
    #pragma unroll
    for (int ds = 0; ds < 8; ++ds) s += sbp[(size_t)(ds*32 + b)*512 + h];
    sbv[ni] = s;
  }
  float* red = reinterpret_cast<float*>(&lds[0]);   // 1024 floats (post-barrier reuse)
  #pragma unroll
  for (int mi = 0; mi < 8; ++mi){
    #pragma unroll
    for (int j = 0; j < 4; ++j){
      float v = 0.f;
      #pragma unroll
      for (int ni = 0; ni < 4; ++ni)
        v += tanh_cheap(tanh_cheap(acc[mi][ni][j] + sbv[ni])) * w2v[ni];
      v += __shfl_xor(v, 1); v += __shfl_xor(v, 2);
      v += __shfl_xor(v, 4); v += __shfl_xor(v, 8);   // sum 16 cols
      if (lr == 0)
        red[wcn*256 + wr*128 + mi*16 + kg*4 + j] = v; // C/D row=(lane>>4)*4+j
    }
  }
  __syncthreads();
  if (t < 256)
    plog[(size_t)nt*65536 + m0 + t] = red[t] + red[256+t] + red[512+t] + red[768+t];
}

// ---------------------------------------------------------------- K2: softmax stats (2 partials)
__global__ __launch_bounds__(256) void k2_softmax(const float* __restrict__ plog,
                                                  const float* __restrict__ mask,
                                                  float* __restrict__ out_logit,
                                                  float* __restrict__ mz){
  const int b = blockIdx.x, t = threadIdx.x;
  float l[8]; float mx = -3.4e38f;
  #pragma unroll
  for (int i = 0; i < 8; ++i){
    const size_t idx = (size_t)b*2048 + t + i*256;
    float v = plog[idx] + plog[65536 + idx];
    v -= NEG_BIG * (1.0f - mask[idx]);
    l[i] = v;
    out_logit[idx] = v;
    mx = fmaxf(mx, v);
  }
  __shared__ float red[8];
  const int wid = t >> 6, lane = t & 63;
  #pragma unroll
  for (int off = 1; off < 64; off <<= 1) mx = fmaxf(mx, __shfl_xor(mx, off));
  if (lane == 0) red[wid] = mx;
  __syncthreads();
  mx = fmaxf(fmaxf(red[0], red[1]), fmaxf(red[2], red[3]));
  float zs = 0.f;
  #pragma unroll
  for (int i = 0; i < 8; ++i) zs += __expf(l[i] - mx);
  #pragma unroll
  for (int off = 1; off < 64; off <<= 1) zs += __shfl_xor(zs, off);
  if (lane == 0) red[4 + wid] = zs;
  __syncthreads();
  if (t == 0){ mz[b*2] = mx; mz[b*2+1] = red[4]+red[5]+red[6]+red[7]; }
}

// ---------------------------------------------------------------- K3: pooled partials (fp32, float4/thread)
__global__ __launch_bounds__(256) void k3_pool(const float* __restrict__ input,
                                               const float* __restrict__ logit,
                                               const float* __restrict__ mz,
                                               float* __restrict__ pool){
  const int b = blockIdx.x >> 4, sc = blockIdx.x & 15;
  const int t = threadIdx.x;
  __shared__ float p[128];
  const float m = mz[b*2], invZ = 1.0f / mz[b*2+1];
  if (t < 128) p[t] = __expf(logit[(size_t)b*2048 + sc*128 + t] - m) * invZ;
  __syncthreads();
  const int half = t >> 7, cw = t & 127;
  float a0=0.f,a1=0.f,a2=0.f,a3=0.f;
  const float* base = input + ((size_t)b*2048 + sc*128 + half)*512 + cw*4;
  #pragma unroll 4
  for (int i = 0; i < 64; ++i){
    const float4 v = *reinterpret_cast<const float4*>(base + (size_t)i*1024);
    const float pv = p[half + 2*i];
    a0 += pv*v.x; a1 += pv*v.y; a2 += pv*v.z; a3 += pv*v.w;
  }
  float4 o = {a0,a1,a2,a3};
  *reinterpret_cast<float4*>(pool + (size_t)blockIdx.x*1024 + half*512 + cw*4) = o;
}

// ---------------------------------------------------------------- K4: reduce partials (32 chunks/batch)
__global__ __launch_bounds__(256) void k4_reduce(const float* __restrict__ pool,
                                                 float* __restrict__ out_pooled){
  const int tg = blockIdx.x*256 + threadIdx.x;  // 0..16383
  const int b = tg >> 9, d = tg & 511;
  float s = 0.f;
  #pragma unroll
  for (int c = 0; c < 32; ++c) s += pool[((size_t)b*32 + c)*512 + d];
  out_pooled[tg] = s;
}

// ---------------------------------------------------------------- launch
extern "C" void kernel_launch(void* const* d_in, const int* in_sizes, int n_in,
                              void* d_out, int out_size, void* d_ws, size_t ws_size,
                              hipStream_t stream){
  const float* input = (const float*)d_in[0];
  const float* state = (const float*)d_in[1];
  const float* mask  = (const float*)d_in[2];
  const float* W1    = (const float*)d_in[3];
  const float* w2    = (const float*)d_in[4];

  float* out_pooled = (float*)d_out;
  float* out_logit  = (float*)d_out + 16384;

  char* ws = (char*)d_ws;
  float*          sbp  = (float*)(ws);                   // 512 KB
  unsigned short* w1xt = (unsigned short*)(ws + 524288); // 512 KB
  float*          plog = (float*)(ws + 1048576);         // 512 KB (2 partials)
  float*          mz   = (float*)(ws + 1572864);         // 256 B
  float*          pool = (float*)(ws + 1573120);         // 2 MB
  (void)ws_size; (void)in_sizes; (void)n_in; (void)out_size;

  k0_prep    <<<320, 256, 0, stream>>>(state, W1, sbp, w1xt);
  k1_gemm_8ph<<<512, 512, 0, stream>>>(input, w1xt, sbp, w2, plog);
  k2_softmax <<<32,  256, 0, stream>>>(plog, mask, out_logit, mz);
  k3_pool    <<<512, 256, 0, stream>>>(input, out_logit, mz, pool);
  k4_reduce  <<<64,  256, 0, stream>>>(pool, out_pooled);
}

// Round 23
// 97.168 us; speedup vs baseline: 1.1381x; 1.1381x over previous
//
#include <hip/hip_runtime.h>
#include <cstdint>
#include <cstddef>

// Problem: B=32, S=2048, D=512, H=512
//   sb[b,h]   = state @ W1[:D]
//   h         = tanh(tanh(sb + input@W1[D:]))   <-- DOUBLE tanh (reference quirk)
//   logit[b,s]= sum_h h * w2[h]  - 1e30*(1-mask)
//   p = softmax over S;  pooled[b,d] = sum_s p*input
// Outputs: pooled (16384 f32) ++ logit (65536 f32)
//
// r23: r19 (best verified, 97.2us, no spills) + corrected counted vmcnt gates:
// even-kt q1 end -> vmcnt(4): retires A(kt+1) [issued FIRST at q0, in-order],
// leaves B(bt+1)'s 4 loads in flight until odd-kt q1 vmcnt(0) (one phase before
// its kt+2 consumption). r19 drained vmcnt(0) everywhere, wasting B's prefetch
// depth. Fused-A line closed: r20-22 all spilled (WRITE_SIZE 19-37 MB).

#define NEG_BIG 1e30f

typedef __attribute__((ext_vector_type(8))) short short8_t;   // 8 x bf16
typedef __attribute__((ext_vector_type(4))) float f32x4;

__device__ inline unsigned short f2bf(float f){
  union { float f; unsigned int u; } v; v.f = f;
  unsigned int r = v.u + 0x7fffu + ((v.u >> 16) & 1u);   // RNE
  return (unsigned short)(r >> 16);
}
// tanh via 1 - 2/(1+e^{2x}): exp overflow -> inf -> rcp -> 0 -> +1; underflow -> -1.
__device__ inline float tanh_cheap(float x){
  return 1.0f - 2.0f*__builtin_amdgcn_rcpf(1.0f + __expf(2.0f*x));
}

typedef __attribute__((address_space(1))) const unsigned int g_u32;
typedef __attribute__((address_space(3))) unsigned int l_u32;
__device__ inline void gload16(const void* g, void* l){
  __builtin_amdgcn_global_load_lds((g_u32*)g, (l_u32*)l, 16, 0, 0);
}

// ---------------------------------------------------------------- K0: prep (tiny)
__global__ __launch_bounds__(256) void k0_prep(const float* __restrict__ state,
                                               const float* __restrict__ W1,
                                               float* __restrict__ sbp,
                                               unsigned short* __restrict__ w1xt){
  const int bid = blockIdx.x, t = threadIdx.x;
  if (bid < 64) {
    const int k0 = (bid >> 3) * 64, h0 = (bid & 7) * 64;
    __shared__ float tile[64][65];
    const int c = t & 63, r0 = t >> 6;
    #pragma unroll
    for (int i = 0; i < 16; ++i){
      int r = r0 + 4*i;
      tile[r][c] = W1[(size_t)(512 + k0 + r)*512 + h0 + c];
    }
    __syncthreads();
    #pragma unroll
    for (int i = 0; i < 16; ++i){
      int r = r0 + 4*i;
      w1xt[(size_t)(h0 + r)*512 + k0 + c] = f2bf(tile[c][r]);
    }
  } else {
    const int idx = bid - 64;               // 0..255
    const int b = idx >> 3, ds = idx & 7;
    __shared__ float stl[64];
    if (t < 64) stl[t] = state[b*512 + ds*64 + t];
    __syncthreads();
    float acc0 = 0.f, acc1 = 0.f;
    #pragma unroll 8
    for (int i = 0; i < 64; ++i){
      const float w = stl[i];
      acc0 += w * W1[(size_t)(ds*64 + i)*512 + t];
      acc1 += w * W1[(size_t)(ds*64 + i)*512 + t + 256];
    }
    sbp[(size_t)(ds*32 + b)*512 + t]       = acc0;
    sbp[(size_t)(ds*32 + b)*512 + t + 256] = acc1;
  }
}

// ---------------------------------------------------------------- K1: 256x256 GEMM, fp32-A in LDS, balanced phases
// (r19 kernel verbatim except the q1-end gates.)
// A: BK=32 f32 (128B rows, phys = c^(row&7)). B: BK=64 bf16 (128B rows, same swizzle).
// LDS 128KB: A 2x32KB @0, B 2x32KB @ushort 32768.
// kt q0: {READ_A lo-half, READ_B all; STAGE_A(kt+1) [kt>=1] then STAGE_B(bt+1) [even kt]}
// kt q1: {READ_A hi-half; MFMA; GATE}
// GATE ledger (in-order queue, A issued before B):
//   even kt with B staged (kt<=12): outstanding A(kt+1)4 then B(bt+1)4 -> vmcnt(4)
//     retires A (needed kt+1), leaves B (needed kt+2; gated next odd kt).
//   otherwise (odd kt / kt=14): vmcnt(0).
__global__ __launch_bounds__(512, 1) void k1_gemm_f32a(const float* __restrict__ input,
                                                       const unsigned short* __restrict__ w1xt,
                                                       const float* __restrict__ sbp,
                                                       const float* __restrict__ w2,
                                                       float* __restrict__ plog){
  __shared__ unsigned short lds[65536];   // 128 KB

  const int orig = blockIdx.x;            // 512 blocks, bijective XCD swizzle (512%8==0)
  const int xcd = orig & 7, qq = orig >> 3;
  const int mtile = xcd*32 + (qq >> 1);
  const int nt = qq & 1;                  // nt 0/1 of same mtile adjacent -> A L2 reuse
  const int m0 = mtile*256, n0 = nt*256;
  const int b = m0 >> 11;

  const int t = threadIdx.x;
  const int lane = t & 63, wid = t >> 6;
  const int wr = wid >> 2, wcn = wid & 3;
  const int lr = lane & 15, kg = lane >> 4;
  const int l7 = lr & 7;

  // staging sources (inverse-swizzled per-lane global addr; LDS dest linear)
  const int srow = t >> 3;                               // 0..63
  const int sinv = (t & 7) ^ ((t >> 3) & 7);             // inverse-swizzled 16B chunk
  const float*          gA  = input + (size_t)(m0 + srow)*512 + sinv*4;  // 4 f32/chunk
  const unsigned short* gBp = w1xt  + (size_t)(n0 + srow)*512 + sinv*8;  // 8 bf16/chunk

  f32x4 acc[8][4];
  #pragma unroll
  for (int mi = 0; mi < 8; ++mi)
    #pragma unroll
    for (int ni = 0; ni < 4; ++ni) acc[mi][ni] = (f32x4){0.f,0.f,0.f,0.f};

  short8_t af[4], bf[4];

  // A tile = 256 rows x 32 f32 = 32 KB = 4 gloads (64 rows each)
#define STAGE_A(KT) do{ \
    const float* gs_ = gA + (KT)*32; \
    const unsigned db_ = (unsigned)((((KT)&1)*16384) + wid*512); \
    gload16(gs_,             &lds[db_]); \
    gload16(gs_ +  64*512,   &lds[db_ + 4096]); \
    gload16(gs_ + 128*512,   &lds[db_ + 8192]); \
    gload16(gs_ + 192*512,   &lds[db_ + 12288]); }while(0)

  // B tile = 256 rows x 64 bf16 = 32 KB = 4 gloads (64 rows each); BT = kt>>1
#define STAGE_B(BT) do{ \
    const unsigned short* gs_ = gBp + (BT)*64; \
    const unsigned db_ = 32768u + (unsigned)((((BT)&1)*16384) + wid*512); \
    gload16(gs_,             &lds[db_]); \
    gload16(gs_ +  64*512,   &lds[db_ + 4096]); \
    gload16(gs_ + 128*512,   &lds[db_ + 8192]); \
    gload16(gs_ + 192*512,   &lds[db_ + 12288]); }while(0)

  // read one mi-half (4 fragments): 8x ds_read_b128 (f32) + 16x cvt_pk -> bf16
#define READ_A_HALF(MH, KT) do{ \
    const unsigned ab_ = (unsigned)(((KT)&1)*16384); \
    _Pragma("unroll") for (int mm = 0; mm < 4; ++mm){ \
      const unsigned r_ = (unsigned)(wr*128 + ((MH)*4+mm)*16 + lr); \
      f32x4 lo_ = *(const f32x4*)&lds[ab_ + r_*64 + (unsigned)(((2*kg    ) ^ l7)*8)]; \
      f32x4 hi_ = *(const f32x4*)&lds[ab_ + r_*64 + (unsigned)(((2*kg + 1) ^ l7)*8)]; \
      union { short8_t s; unsigned u[4]; } pk_; \
      asm("v_cvt_pk_bf16_f32 %0, %1, %2" : "=v"(pk_.u[0]) : "v"(lo_[0]), "v"(lo_[1])); \
      asm("v_cvt_pk_bf16_f32 %0, %1, %2" : "=v"(pk_.u[1]) : "v"(lo_[2]), "v"(lo_[3])); \
      asm("v_cvt_pk_bf16_f32 %0, %1, %2" : "=v"(pk_.u[2]) : "v"(hi_[0]), "v"(hi_[1])); \
      asm("v_cvt_pk_bf16_f32 %0, %1, %2" : "=v"(pk_.u[3]) : "v"(hi_[2]), "v"(hi_[3])); \
      af[mm] = pk_.s; \
    } }while(0)

  // B fragments, all 4 ni: logical chunk = (kt&1)*4 + kg; phys = c ^ l7
#define READ_B_ALL(KT) do{ \
    const unsigned bb_ = 32768u + (unsigned)((((KT)>>1)&1)*16384); \
    const unsigned h4_ = (unsigned)(((KT)&1)*4); \
    _Pragma("unroll") for (int nn = 0; nn < 4; ++nn){ \
      const unsigned rw_ = (unsigned)(wcn*64 + nn*16 + lr); \
      bf[nn] = *(const short8_t*)&lds[bb_ + rw_*64 + (unsigned)(((h4_ + kg) ^ l7)*8)]; } }while(0)

#define MFMA16(MH) do{ \
    __builtin_amdgcn_s_setprio(1); \
    _Pragma("unroll") for (int mm = 0; mm < 4; ++mm) \
      _Pragma("unroll") for (int nn = 0; nn < 4; ++nn) \
        acc[(MH)*4+mm][nn] = __builtin_amdgcn_mfma_f32_16x16x32_bf16(af[mm], bf[nn], acc[(MH)*4+mm][nn], 0,0,0); \
    __builtin_amdgcn_s_setprio(0); }while(0)

  // prologue: A(0) B(0) A(1) = 12 loads; vmcnt(4) -> A(0),B(0) landed, A(1) in flight
  STAGE_A(0); STAGE_B(0); STAGE_A(1);
  asm volatile("s_waitcnt vmcnt(4)" ::: "memory");
  __builtin_amdgcn_s_barrier();

  #pragma unroll
  for (int kt = 0; kt < 16; ++kt){
    // ---- q0: A-lo + B-all reads, stage next tiles (A first -> older in queue)
    READ_A_HALF(0, kt);
    READ_B_ALL(kt);
    if (kt >= 1 && kt + 1 < 16) STAGE_A(kt + 1);
    if ((kt & 1) == 0 && kt + 2 < 16) STAGE_B((kt >> 1) + 1);
    __builtin_amdgcn_s_barrier();
    asm volatile("s_waitcnt lgkmcnt(0)" ::: "memory");
    __builtin_amdgcn_sched_barrier(0);
    MFMA16(0);
    __builtin_amdgcn_s_barrier();
    // ---- q1: A-hi reads (bf held in regs)
    READ_A_HALF(1, kt);
    __builtin_amdgcn_s_barrier();
    asm volatile("s_waitcnt lgkmcnt(0)" ::: "memory");
    __builtin_amdgcn_sched_barrier(0);
    MFMA16(1);
    // ---- corrected counted gate (see header ledger)
    if (kt < 15){
      if ((kt & 1) == 0 && kt + 2 < 16)
        asm volatile("s_waitcnt vmcnt(4)" ::: "memory");   // retire A(kt+1); B stays in flight
      else
        asm volatile("s_waitcnt vmcnt(0)" ::: "memory");   // odd kt / kt=14: drain all
    }
    __builtin_amdgcn_s_barrier();
  }
#undef STAGE_A
#undef STAGE_B
#undef READ_A_HALF
#undef READ_B_ALL
#undef MFMA16

  // epilogue: tanh(tanh(acc + sb)) * w2, reduce over this block's 256 h-cols
  float w2v[4], sbv[4];
  #pragma unroll
  for (int ni = 0; ni < 4; ++ni){
    const int h = n0 + wcn*64 + ni*16 + lr;
    w2v[ni] = w2[h];
    float s = 0.f;
    #pragma unroll
    for (int ds = 0; ds < 8; ++ds) s += sbp[(size_t)(ds*32 + b)*512 + h];
    sbv[ni] = s;
  }
  float* red = reinterpret_cast<float*>(&lds[0]);   // 1024 floats (post-barrier reuse)
  #pragma unroll
  for (int mi = 0; mi < 8; ++mi){
    #pragma unroll
    for (int j = 0; j < 4; ++j){
      float v = 0.f;
      #pragma unroll
      for (int ni = 0; ni < 4; ++ni)
        v += tanh_cheap(tanh_cheap(acc[mi][ni][j] + sbv[ni])) * w2v[ni];
      v += __shfl_xor(v, 1); v += __shfl_xor(v, 2);
      v += __shfl_xor(v, 4); v += __shfl_xor(v, 8);   // sum 16 cols
      if (lr == 0)
        red[wcn*256 + wr*128 + mi*16 + kg*4 + j] = v; // C/D row=(lane>>4)*4+j
    }
  }
  __syncthreads();
  if (t < 256)
    plog[(size_t)nt*65536 + m0 + t] = red[t] + red[256+t] + red[512+t] + red[768+t];
}

// ---------------------------------------------------------------- K2: softmax stats (2 partials)
__global__ __launch_bounds__(256) void k2_softmax(const float* __restrict__ plog,
                                                  const float* __restrict__ mask,
                                                  float* __restrict__ out_logit,
                                                  float* __restrict__ mz){
  const int b = blockIdx.x, t = threadIdx.x;
  float l[8]; float mx = -3.4e38f;
  #pragma unroll
  for (int i = 0; i < 8; ++i){
    const size_t idx = (size_t)b*2048 + t + i*256;
    float v = plog[idx] + plog[65536 + idx];
    v -= NEG_BIG * (1.0f - mask[idx]);
    l[i] = v;
    out_logit[idx] = v;
    mx = fmaxf(mx, v);
  }
  __shared__ float red[8];
  const int wid = t >> 6, lane = t & 63;
  #pragma unroll
  for (int off = 1; off < 64; off <<= 1) mx = fmaxf(mx, __shfl_xor(mx, off));
  if (lane == 0) red[wid] = mx;
  __syncthreads();
  mx = fmaxf(fmaxf(red[0], red[1]), fmaxf(red[2], red[3]));
  float zs = 0.f;
  #pragma unroll
  for (int i = 0; i < 8; ++i) zs += __expf(l[i] - mx);
  #pragma unroll
  for (int off = 1; off < 64; off <<= 1) zs += __shfl_xor(zs, off);
  if (lane == 0) red[4 + wid] = zs;
  __syncthreads();
  if (t == 0){ mz[b*2] = mx; mz[b*2+1] = red[4]+red[5]+red[6]+red[7]; }
}

// ---------------------------------------------------------------- K3: pooled partials (fp32, float4/thread)
__global__ __launch_bounds__(256) void k3_pool(const float* __restrict__ input,
                                               const float* __restrict__ logit,
                                               const float* __restrict__ mz,
                                               float* __restrict__ pool){
  const int b = blockIdx.x >> 4, sc = blockIdx.x & 15;
  const int t = threadIdx.x;
  __shared__ float p[128];
  const float m = mz[b*2], invZ = 1.0f / mz[b*2+1];
  if (t < 128) p[t] = __expf(logit[(size_t)b*2048 + sc*128 + t] - m) * invZ;
  __syncthreads();
  const int half = t >> 7, cw = t & 127;
  float a0=0.f,a1=0.f,a2=0.f,a3=0.f;
  const float* base = input + ((size_t)b*2048 + sc*128 + half)*512 + cw*4;
  #pragma unroll 4
  for (int i = 0; i < 64; ++i){
    const float4 v = *reinterpret_cast<const float4*>(base + (size_t)i*1024);
    const float pv = p[half + 2*i];
    a0 += pv*v.x; a1 += pv*v.y; a2 += pv*v.z; a3 += pv*v.w;
  }
  float4 o = {a0,a1,a2,a3};
  *reinterpret_cast<float4*>(pool + (size_t)blockIdx.x*1024 + half*512 + cw*4) = o;
}

// ---------------------------------------------------------------- K4: reduce partials (32 chunks/batch)
__global__ __launch_bounds__(256) void k4_reduce(const float* __restrict__ pool,
                                                 float* __restrict__ out_pooled){
  const int tg = blockIdx.x*256 + threadIdx.x;  // 0..16383
  const int b = tg >> 9, d = tg & 511;
  float s = 0.f;
  #pragma unroll
  for (int c = 0; c < 32; ++c) s += pool[((size_t)b*32 + c)*512 + d];
  out_pooled[tg] = s;
}

// ---------------------------------------------------------------- launch
extern "C" void kernel_launch(void* const* d_in, const int* in_sizes, int n_in,
                              void* d_out, int out_size, void* d_ws, size_t ws_size,
                              hipStream_t stream){
  const float* input = (const float*)d_in[0];
  const float* state = (const float*)d_in[1];
  const float* mask  = (const float*)d_in[2];
  const float* W1    = (const float*)d_in[3];
  const float* w2    = (const float*)d_in[4];

  float* out_pooled = (float*)d_out;
  float* out_logit  = (float*)d_out + 16384;

  char* ws = (char*)d_ws;
  float*          sbp  = (float*)(ws);                   // 512 KB
  unsigned short* w1xt = (unsigned short*)(ws + 524288); // 512 KB
  float*          plog = (float*)(ws + 1048576);         // 512 KB (2 partials)
  float*          mz   = (float*)(ws + 1572864);         // 256 B
  float*          pool = (float*)(ws + 1573120);         // 2 MB
  (void)ws_size; (void)in_sizes; (void)n_in; (void)out_size;

  k0_prep     <<<320, 256, 0, stream>>>(state, W1, sbp, w1xt);
  k1_gemm_f32a<<<512, 512, 0, stream>>>(input, w1xt, sbp, w2, plog);
  k2_softmax  <<<32,  256, 0, stream>>>(plog, mask, out_logit, mz);
  k3_pool     <<<512, 256, 0, stream>>>(input, out_logit, mz, pool);
  k4_reduce   <<<64,  256, 0, stream>>>(pool, out_pooled);
}